// Round 1
// baseline (458.302 us; speedup 1.0000x reference)
//
#include <hip/hip_runtime.h>
#include <hip/hip_bf16.h>
#include <math.h>

typedef __bf16 bf16;
typedef __attribute__((ext_vector_type(2))) __bf16 bf16x2;
typedef __attribute__((ext_vector_type(4))) __bf16 bf16x4;
typedef __attribute__((ext_vector_type(8))) __bf16 bf16x8;
typedef __attribute__((ext_vector_type(4))) float f32x4;

#define LDS_ASYNC16(gptr, lptr)                                                        \
  __builtin_amdgcn_global_load_lds(                                                    \
      (const __attribute__((address_space(1))) void*)(gptr),                           \
      (__attribute__((address_space(3))) void*)(lptr), 16, 0, 0)

constexpr int BATCH = 2, SEQ = 2048, DIM = 2048, NH = 16, HD = 128;
// 1/sqrt(128) * log2(e): folded into Q at projection; flash works in exp2 domain
constexpr float QSC = 0.12751744f;
constexpr float FREQC = 0.20762050593046f;  // log2(10000)/64

// ---- DPP 16-lane reductions (row_ror rotates within 16-lane rows on gfx9) ----
template <int CTRL>
__device__ __forceinline__ float dpp_mov_f(float x) {
  return __int_as_float(__builtin_amdgcn_update_dpp(
      __float_as_int(x), __float_as_int(x), CTRL, 0xf, 0xf, false));
}
__device__ __forceinline__ float rowmax16(float x) {
  x = fmaxf(x, dpp_mov_f<0x121>(x));  // ror:1
  x = fmaxf(x, dpp_mov_f<0x122>(x));  // ror:2
  x = fmaxf(x, dpp_mov_f<0x124>(x));  // ror:4
  x = fmaxf(x, dpp_mov_f<0x128>(x));  // ror:8
  return x;
}
__device__ __forceinline__ float rowsum16(float x) {
  x += dpp_mov_f<0x121>(x);
  x += dpp_mov_f<0x122>(x);
  x += dpp_mov_f<0x124>(x);
  x += dpp_mov_f<0x128>(x);
  return x;
}

// ---------------------------------------------------------------- fp32 -> bf16
__global__ void cvt_f32_to_bf16(const float4* __restrict__ in,
                                bf16x4* __restrict__ out, int n4) {
  int i = blockIdx.x * blockDim.x + threadIdx.x;
  if (i >= n4) return;
  float4 v = in[i];
  bf16x4 o;
  o[0] = (bf16)v.x; o[1] = (bf16)v.y; o[2] = (bf16)v.z; o[3] = (bf16)v.w;
  out[i] = o;
}

// ------------------------- all 4 weights: W (K,N) fp32 -> W^T (N,K) bf16, z=which
__global__ void transpose_w4(const float* __restrict__ W0, const float* __restrict__ W1,
                             const float* __restrict__ W2, const float* __restrict__ W3,
                             bf16* __restrict__ T0, bf16* __restrict__ T3) {
  __shared__ float tile[32][33];
  const int z = blockIdx.z;
  const float* W = (z == 0) ? W0 : (z == 1) ? W1 : (z == 2) ? W2 : W3;
  bf16* WT = (z == 3) ? T3 : (T0 + (size_t)z * DIM * DIM);
  int tx = threadIdx.x, ty = threadIdx.y;
  int bx = blockIdx.x * 32, by = blockIdx.y * 32;
#pragma unroll
  for (int j = 0; j < 32; j += 8)
    tile[ty + j][tx] = W[(size_t)(by + ty + j) * DIM + bx + tx];
  __syncthreads();
#pragma unroll
  for (int j = 0; j < 32; j += 8)
    WT[(size_t)(bx + ty + j) * DIM + by + tx] = (bf16)tile[tx][ty + j];
}

// ===================== 256x256 8-phase fused QKV GEMM + RoPE =====================
// BM=BN=256, BK=64, 512 thr = 8 waves (2M x 4N), wave tile 128x64.
// LDS: per matrix 4 regions (2 buf x 2 k-half), each 256 rows x 32 k bf16 = 16 KB.
// Region chunk swizzle: phys 16B-chunk p at (row, logical kc): p = kc ^ ((row>>1)&3)
// -> quarter-wave ds_read_b128 lands 2 lanes/4-bank-group (free, m136).
// Schedule per K-tile t (buf b=t&1), phases P1..P4; each phase =
//   {ds_read frags; stage 1 half (2 gload_lds); bar; lgkm(0); 16 MFMA; bar}:
//   P1 reads A(b,kh0)mf0-3 + B(b,kh0)        stages A(t+1,kh1)   [A(b^1,1) freed (t-1).P4]
//   P2 reads A(b,kh0)mf4-7 (B in regs)       stages B(t+2,kh0)   [B(b,0)  freed P1]
//   P3 reads A(b,kh1)mf0-3 + B(b,kh1)        stages A(t+2,kh0)   [A(b,0)  freed P2]
//   P4 reads A(b,kh1)mf4-7                   stages B(t+2,kh1)   [B(b,1)  freed P3]
//   P4 ends with s_waitcnt vmcnt(6): leaves exactly the last 3 staged halves in
//   flight; guarantees all of tile t+1 (incl. A(t+1,kh1) staged t.P1) has landed.
__device__ __forceinline__ void stage_half(const bf16* __restrict__ src, int g0, int ks,
                                           bf16* lds, int w, int lane) {
#pragma unroll
  for (int j = 0; j < 2; ++j) {
    const int u = (j * 8 + w) * 64 + lane;            // 16B-slot index in region
    const int row = u >> 2;                           // 4 slots/row
    const int kc = (u & 3) ^ ((u >> 3) & 3);          // inverse swizzle on SOURCE
    LDS_ASYNC16(src + (size_t)(g0 + row) * DIM + ks + kc * 8,
                lds + (size_t)((j * 8 + w) * 64) * 8);  // linear LDS dest (+lane*16B)
  }
}

__global__ __launch_bounds__(512) void gemm_qkv(const bf16* __restrict__ A,
                                                const bf16* __restrict__ BT,
                                                bf16* __restrict__ Qb,
                                                bf16* __restrict__ Kb,
                                                bf16* __restrict__ VTo) {
  constexpr int RSZ = 256 * 32;  // elements per (buf,kh) region
  constexpr int NT = DIM / 64;   // 32 K-tiles
  __shared__ __attribute__((aligned(16))) bf16 As[4 * RSZ];  // 64 KB
  __shared__ __attribute__((aligned(16))) bf16 Bs[4 * RSZ];  // 64 KB
  const int tid = threadIdx.x;
  const int w = tid >> 6, lane = tid & 63;
  const int quad = lane >> 4, ln = lane & 15;
  const int wm = w >> 2, wn = w & 3;
  // bijective XCD swizzle: 384 wgs -> 48/XCD = 2 consecutive A-panels per XCD L2
  const int lb = blockIdx.x;
  const int wgid = (lb & 7) * 48 + (lb >> 3);
  const int bx = wgid % 24, by = wgid / 24;
  const int m0 = by * 256, n0 = bx * 256;
  const int pc = (quad ^ ((ln >> 1) & 3)) * 8;  // swizzled read chunk (lane-const)
  const int aoff = wm * 128 + ln;
  const int boff = wn * 64 + ln;

  f32x4 acc[8][4] = {};

  // prologue: tile0 all 4 halves + tile1 {A kh0, B kh0, B kh1}; A(1,kh1) comes at t0.P1
  stage_half(A,  m0, 0,  As + 0 * RSZ, w, lane);
  stage_half(BT, n0, 0,  Bs + 0 * RSZ, w, lane);
  stage_half(A,  m0, 32, As + 1 * RSZ, w, lane);
  stage_half(BT, n0, 32, Bs + 1 * RSZ, w, lane);
  stage_half(A,  m0, 64, As + 2 * RSZ, w, lane);
  stage_half(BT, n0, 64, Bs + 2 * RSZ, w, lane);
  stage_half(BT, n0, 96, Bs + 3 * RSZ, w, lane);
  asm volatile("s_waitcnt vmcnt(6)" ::: "memory");  // tile0's 8 loads landed
  __builtin_amdgcn_s_barrier();

#pragma unroll 2
  for (int t = 0; t < NT; ++t) {
    const int b2 = (t & 1) * 2;
    const bf16* Ab0 = As + b2 * RSZ;
    const bf16* Ab1 = Ab0 + RSZ;
    const bf16* Bb0 = Bs + b2 * RSZ;
    const bf16* Bb1 = Bb0 + RSZ;
    bf16x8 af[4], bfr[4];

    // ---- P1: mf0-3 x nf0-3, kh0
#pragma unroll
    for (int i = 0; i < 4; ++i)
      af[i] = *(const bf16x8*)(Ab0 + (aoff + i * 16) * 32 + pc);
#pragma unroll
    for (int i = 0; i < 4; ++i)
      bfr[i] = *(const bf16x8*)(Bb0 + (boff + i * 16) * 32 + pc);
    if (t + 1 < NT)
      stage_half(A, m0, (t + 1) * 64 + 32, As + ((((t + 1) & 1) * 2) + 1) * RSZ, w, lane);
    __builtin_amdgcn_s_barrier();
    asm volatile("s_waitcnt lgkmcnt(0)" ::: "memory");
    __builtin_amdgcn_s_setprio(1);
#pragma unroll
    for (int mf = 0; mf < 4; ++mf)
#pragma unroll
      for (int nf = 0; nf < 4; ++nf)
        acc[mf][nf] = __builtin_amdgcn_mfma_f32_16x16x32_bf16(
            af[mf], bfr[nf], acc[mf][nf], 0, 0, 0);
    __builtin_amdgcn_s_setprio(0);
    __builtin_amdgcn_s_barrier();

    // ---- P2: mf4-7 x nf0-3, kh0 (B frags reused from registers)
#pragma unroll
    for (int i = 0; i < 4; ++i)
      af[i] = *(const bf16x8*)(Ab0 + (aoff + 64 + i * 16) * 32 + pc);
    if (t + 2 < NT)
      stage_half(BT, n0, (t + 2) * 64, Bs + b2 * RSZ, w, lane);
    __builtin_amdgcn_s_barrier();
    asm volatile("s_waitcnt lgkmcnt(0)" ::: "memory");
    __builtin_amdgcn_s_setprio(1);
#pragma unroll
    for (int mf = 0; mf < 4; ++mf)
#pragma unroll
      for (int nf = 0; nf < 4; ++nf)
        acc[4 + mf][nf] = __builtin_amdgcn_mfma_f32_16x16x32_bf16(
            af[mf], bfr[nf], acc[4 + mf][nf], 0, 0, 0);
    __builtin_amdgcn_s_setprio(0);
    __builtin_amdgcn_s_barrier();

    // ---- P3: mf0-3 x nf0-3, kh1
#pragma unroll
    for (int i = 0; i < 4; ++i)
      af[i] = *(const bf16x8*)(Ab1 + (aoff + i * 16) * 32 + pc);
#pragma unroll
    for (int i = 0; i < 4; ++i)
      bfr[i] = *(const bf16x8*)(Bb1 + (boff + i * 16) * 32 + pc);
    if (t + 2 < NT)
      stage_half(A, m0, (t + 2) * 64, As + b2 * RSZ, w, lane);
    __builtin_amdgcn_s_barrier();
    asm volatile("s_waitcnt lgkmcnt(0)" ::: "memory");
    __builtin_amdgcn_s_setprio(1);
#pragma unroll
    for (int mf = 0; mf < 4; ++mf)
#pragma unroll
      for (int nf = 0; nf < 4; ++nf)
        acc[mf][nf] = __builtin_amdgcn_mfma_f32_16x16x32_bf16(
            af[mf], bfr[nf], acc[mf][nf], 0, 0, 0);
    __builtin_amdgcn_s_setprio(0);
    __builtin_amdgcn_s_barrier();

    // ---- P4: mf4-7 x nf0-3, kh1
#pragma unroll
    for (int i = 0; i < 4; ++i)
      af[i] = *(const bf16x8*)(Ab1 + (aoff + 64 + i * 16) * 32 + pc);
    if (t + 2 < NT)
      stage_half(BT, n0, (t + 2) * 64 + 32, Bs + (b2 + 1) * RSZ, w, lane);
    __builtin_amdgcn_s_barrier();
    asm volatile("s_waitcnt lgkmcnt(0)" ::: "memory");
    __builtin_amdgcn_s_setprio(1);
#pragma unroll
    for (int mf = 0; mf < 4; ++mf)
#pragma unroll
      for (int nf = 0; nf < 4; ++nf)
        acc[4 + mf][nf] = __builtin_amdgcn_mfma_f32_16x16x32_bf16(
            af[mf], bfr[nf], acc[4 + mf][nf], 0, 0, 0);
    __builtin_amdgcn_s_setprio(0);
    // counted drain: keep last 3 staged halves in flight; full drain near tail
    if (t + 2 < NT) asm volatile("s_waitcnt vmcnt(6)" ::: "memory");
    else            asm volatile("s_waitcnt vmcnt(0)" ::: "memory");
    __builtin_amdgcn_s_barrier();
  }

  // ---------------- epilogue: Q (RoPE*QSC) / K (RoPE) / V^T ----------------
  const int sel = n0 >> 11;  // bx 0-7: Q, 8-15: K, 16-23: V (block-uniform)
  if (sel == 2) {
#pragma unroll
    for (int mf = 0; mf < 8; ++mf)
#pragma unroll
      for (int nf = 0; nf < 4; ++nf) {
        int gr = m0 + wm * 128 + mf * 16 + quad * 4;
        int fc = (n0 + wn * 64 + nf * 16 + ln) & 2047;
        int bb = gr >> 11, s0 = gr & (SEQ - 1);
        int h = fc >> 7, d = fc & (HD - 1);
        bf16x4 pk;
#pragma unroll
        for (int r = 0; r < 4; ++r) pk[r] = (bf16)acc[mf][nf][r];
        *(bf16x4*)(VTo + ((size_t)((bb * NH + h) * HD + d)) * SEQ + s0) = pk;
      }
  } else {
    bf16* Dst = sel ? Kb : Qb;
    const float osc = sel ? 1.0f : QSC;
#pragma unroll
    for (int nf = 0; nf < 4; ++nf) {
      int gc = n0 + wn * 64 + nf * 16 + ln;
      int fc = gc & 2047, d = fc & (HD - 1);
      float freq = exp2f(-(float)(d >> 1) * FREQC);
      bool ev = !(d & 1);
#pragma unroll
      for (int mf = 0; mf < 8; ++mf) {
#pragma unroll
        for (int r = 0; r < 4; ++r) {
          int gr = m0 + wm * 128 + mf * 16 + quad * 4 + r;
          int s = gr & (SEQ - 1);
          float ang = (float)s * freq;
          float sn, cs;
          __sincosf(ang, &sn, &cs);
          float own = acc[mf][nf][r];
          float oth = __shfl_xor(own, 1);  // partner feature (d^1), lane ln^1
          float res = ev ? (own * cs - oth * sn) : (oth * sn + own * cs);
          Dst[(size_t)gr * DIM + fc] = (bf16)(res * osc);
        }
      }
    }
  }
}

// --------------------------------------------------------------------- GEMM
// C[M,N] = A * BT^T; MODE 2: C fp32 row-major (used for the Wo projection).
template <int MODE>
__global__ __launch_bounds__(256) void gemm_bt(const bf16* __restrict__ A,
                                               const bf16* __restrict__ BT,
                                               void* __restrict__ C) {
  __shared__ __attribute__((aligned(16))) bf16 As[128 * 64];
  __shared__ __attribute__((aligned(16))) bf16 Bs[128 * 64];
  const int tid = threadIdx.x;
  const int w = tid >> 6, lane = tid & 63;
  const int quad = lane >> 4, ln = lane & 15;
  const int m0 = blockIdx.y * 128, n0 = blockIdx.x * 128;
  const int wm = (w >> 1) * 64, wn = (w & 1) * 64;
  const int l7 = ln & 7;
  f32x4 acc[4][4] = {};

  for (int k0 = 0; k0 < DIM; k0 += 64) {
#pragma unroll
    for (int i = 0; i < 4; ++i) {
      const int c = i * 256 + tid;
      const int row = c >> 3, p = c & 7;
      LDS_ASYNC16(A  + (size_t)(m0 + row) * DIM + k0 + ((p ^ (row & 7)) * 8),
                  As + (size_t)(i * 256 + w * 64) * 8);
      LDS_ASYNC16(BT + (size_t)(n0 + row) * DIM + k0 + ((p ^ (row & 7)) * 8),
                  Bs + (size_t)(i * 256 + w * 64) * 8);
    }
    __syncthreads();
#pragma unroll
    for (int kh = 0; kh < 2; ++kh) {
      bf16x8 af[4], bfr[4];
#pragma unroll
      for (int t = 0; t < 4; ++t)
        af[t] = *(const bf16x8*)(As + (wm + t * 16 + ln) * 64 +
                                 (((kh * 4 + quad) ^ l7) * 8));
#pragma unroll
      for (int t = 0; t < 4; ++t)
        bfr[t] = *(const bf16x8*)(Bs + (wn + t * 16 + ln) * 64 +
                                  (((kh * 4 + quad) ^ l7) * 8));
#pragma unroll
      for (int mt = 0; mt < 4; ++mt)
#pragma unroll
        for (int nt = 0; nt < 4; ++nt)
          acc[mt][nt] = __builtin_amdgcn_mfma_f32_16x16x32_bf16(
              af[mt], bfr[nt], acc[mt][nt], 0, 0, 0);
    }
    __syncthreads();
  }

  if (MODE == 0) {
    bf16* Co = (bf16*)C;
#pragma unroll
    for (int mt = 0; mt < 4; ++mt)
#pragma unroll
      for (int nt = 0; nt < 4; ++nt) {
        int gr = m0 + wm + mt * 16 + quad * 4;
        int gc = n0 + wn + nt * 16 + ln;
#pragma unroll
        for (int r = 0; r < 4; ++r)
          Co[(size_t)(gr + r) * DIM + gc] = (bf16)acc[mt][nt][r];
      }
  } else {
    float* Co = (float*)C;
#pragma unroll
    for (int mt = 0; mt < 4; ++mt)
#pragma unroll
      for (int nt = 0; nt < 4; ++nt) {
        int gr = m0 + wm + mt * 16 + quad * 4;
        int gc = n0 + wn + nt * 16 + ln;
#pragma unroll
        for (int r = 0; r < 4; ++r)
          Co[(size_t)(gr + r) * DIM + gc] = acc[mt][nt][r];
      }
  }
}

// -------------------------- flash split-K chunk bookkeeping (chunk = 10 k-tiles)
// Per (b,h): t=0..4 direct (1 chunk); t=5..9: 2 chunks; t=10..14: 3; t=15: 4.
// 34 blocks/bh. Chunk 0 of a chunked tile writes unnormalized bf16 into O's
// final location; chunks >=1 go to Opart. All chunks write M/L.
__device__ __forceinline__ int ml_off(int t) {  // per-bh M/L slot base, stride 29
  return (t < 10) ? 2 * (t - 5) : (t < 15) ? 10 + 3 * (t - 10) : 25;
}
__device__ __forceinline__ int op_off(int t) {  // per-bh Opart slot base, stride 18
  return (t < 10) ? (t - 5) : (t < 15) ? 5 + 2 * (t - 10) : 15;
}

constexpr int PSTR = 72;
// 1-D grid, XCD-swizzled: lb = ((bh>>3)*34 + e)*8 + (bh&7), so lb%8 (the XCD
// on the 8-XCD round-robin) is constant per bh -> one bh's 1 MB of K/V stays
// in one XCD's L2 (4 bh x 1 MB per XCD) instead of being fetched by all 8.
__global__ __launch_bounds__(256) void flash_attn(
    const bf16* __restrict__ Q, const bf16* __restrict__ K,
    const bf16* __restrict__ VT, bf16* __restrict__ O,
    bf16* __restrict__ Opart, float* __restrict__ Mpart,
    float* __restrict__ Lpart) {
  __shared__ __attribute__((aligned(16))) bf16 Ks[64 * 128];
  __shared__ __attribute__((aligned(16))) bf16 VTs[128 * 64];
  __shared__ __attribute__((aligned(16))) bf16 Ps[4][32 * PSTR];
  const int tid = threadIdx.x;
  const int w = tid >> 6, lane = tid & 63, quad = lane >> 4, ln = lane & 15;
  const int lb = blockIdx.x;
  const int low3 = lb & 7, rest = lb >> 3;
  const int e = rest % 34;
  const int bh = (rest / 34) * 8 + low3;
  int t, c0, nc;
  if (e < 5)       { t = e;                  c0 = 0;               nc = 1; }
  else if (e < 15) { t = 5 + ((e - 5) >> 1); c0 = (e - 5) & 1;     nc = 2; }
  else if (e < 30) { int q = (e - 15) / 3;   t = 10 + q; c0 = (e - 15) - 3 * q; nc = 3; }
  else             { t = 15;                 c0 = e - 30;          nc = 4; }
  const int q0 = t * 128;
  const int ktN = 2 * (t + 1);
  const int kt0 = c0 * 10;
  const int kt1 = min(kt0 + 10, ktN);
  const bool chunked = (nc > 1);
  const int b = bh >> 4, h = bh & 15;

  bf16x8 qf[2][4];
#pragma unroll
  for (int mt = 0; mt < 2; ++mt)
#pragma unroll
    for (int kc = 0; kc < 4; ++kc)
      qf[mt][kc] = *(const bf16x8*)(Q + ((size_t)b * SEQ + q0 + w * 32 + mt * 16 + ln) * DIM +
                                    h * HD + kc * 32 + quad * 8);
  f32x4 o[2][8] = {};
  float mst[2][4], lst[2][4];
#pragma unroll
  for (int mt = 0; mt < 2; ++mt)
#pragma unroll
    for (int r = 0; r < 4; ++r) { mst[mt][r] = -1e30f; lst[mt][r] = 0.f; }

  for (int kt = kt0; kt < kt1; ++kt) {
    __syncthreads();
#pragma unroll
    for (int i = 0; i < 4; ++i) {
      const int c = i * 256 + tid;
      LDS_ASYNC16(K + ((size_t)b * SEQ + kt * 64 + (c >> 4)) * DIM + h * HD +
                      (((c & 15) ^ ((c >> 4) & 15)) * 8),
                  Ks + (size_t)(i * 256 + w * 64) * 8);
      LDS_ASYNC16(VT + ((size_t)((b * NH + h) * HD) + (c >> 3)) * SEQ + kt * 64 +
                      (((c & 7) ^ ((c >> 3) & 7)) * 8),
                  VTs + (size_t)(i * 256 + w * 64) * 8);
    }
    __syncthreads();

    // S = Q K^T (exp2 domain; scale pre-folded into Q)
    f32x4 s[2][4] = {};
#pragma unroll
    for (int nt = 0; nt < 4; ++nt) {
      bf16x8 kf[4];
#pragma unroll
      for (int kc = 0; kc < 4; ++kc)
        kf[kc] = *(const bf16x8*)(Ks + (nt * 16 + ln) * 128 +
                                  (((kc * 4 + quad) ^ ln) * 8));
#pragma unroll
      for (int kc = 0; kc < 4; ++kc)
#pragma unroll
        for (int mt = 0; mt < 2; ++mt)
          s[mt][nt] = __builtin_amdgcn_mfma_f32_16x16x32_bf16(
              qf[mt][kc], kf[kc], s[mt][nt], 0, 0, 0);
    }

    const bool diag = (kt * 64 + 63 > q0);
    if (diag) {
#pragma unroll
      for (int mt = 0; mt < 2; ++mt)
#pragma unroll
        for (int nt = 0; nt < 4; ++nt)
#pragma unroll
          for (int r = 0; r < 4; ++r) {
            int kg = kt * 64 + nt * 16 + ln;
            int qg = q0 + w * 32 + mt * 16 + quad * 4 + r;
            if (kg > qg) s[mt][nt][r] = -1e30f;
          }
    }

    // online softmax, exp2 domain; DPP 16-lane max (no LDS shuffles)
#pragma unroll
    for (int mt = 0; mt < 2; ++mt)
#pragma unroll
      for (int r = 0; r < 4; ++r) {
        float rm = fmaxf(fmaxf(s[mt][0][r], s[mt][1][r]),
                         fmaxf(s[mt][2][r], s[mt][3][r]));
        rm = rowmax16(rm);
        float mold = mst[mt][r];
        float mnew = fmaxf(mold, rm);
        float alpha = exp2f(mold - mnew);
        mst[mt][r] = mnew;
        float rs = 0.f;
#pragma unroll
        for (int nt = 0; nt < 4; ++nt) {
          float p = exp2f(s[mt][nt][r] - mnew);
          rs += p;
          Ps[w][(mt * 16 + quad * 4 + r) * PSTR + nt * 16 + ln] = (bf16)p;
        }
        lst[mt][r] = lst[mt][r] * alpha + rs;
#pragma unroll
        for (int nd = 0; nd < 8; ++nd) o[mt][nd][r] *= alpha;
      }
    __syncthreads();

    // O += P V
#pragma unroll
    for (int kc2 = 0; kc2 < 2; ++kc2) {
      bf16x8 pf[2];
#pragma unroll
      for (int mt = 0; mt < 2; ++mt)
        pf[mt] = *(const bf16x8*)(&Ps[w][(mt * 16 + ln) * PSTR + kc2 * 32 + quad * 8]);
#pragma unroll
      for (int nd = 0; nd < 8; ++nd) {
        bf16x8 vf = *(const bf16x8*)(VTs + (nd * 16 + ln) * 64 +
                                     (((kc2 * 4 + quad) ^ (ln & 7)) * 8));
#pragma unroll
        for (int mt = 0; mt < 2; ++mt)
          o[mt][nd] = __builtin_amdgcn_mfma_f32_16x16x32_bf16(
              pf[mt], vf, o[mt][nd], 0, 0, 0);
      }
    }
  }

  if (!chunked) {
#pragma unroll
    for (int mt = 0; mt < 2; ++mt)
#pragma unroll
      for (int r = 0; r < 4; ++r) {
        float inv = 1.f / rowsum16(lst[mt][r]);
        int qg = q0 + w * 32 + mt * 16 + quad * 4 + r;
#pragma unroll
        for (int nd = 0; nd < 8; ++nd)
          O[((size_t)b * SEQ + qg) * DIM + h * HD + nd * 16 + ln] =
              (bf16)(o[mt][nd][r] * inv);
      }
  } else {
    const int mls = bh * 29 + ml_off(t) + c0;
    bf16* Op = (c0 == 0) ? nullptr
                         : Opart + (size_t)(bh * 18 + op_off(t) + (c0 - 1)) * (128 * 128);
#pragma unroll
    for (int mt = 0; mt < 2; ++mt)
#pragma unroll
      for (int r = 0; r < 4; ++r) {
        float l = rowsum16(lst[mt][r]);
        int qr = w * 32 + mt * 16 + quad * 4 + r;
        if (ln == 0) {
          Mpart[mls * 128 + qr] = mst[mt][r];
          Lpart[mls * 128 + qr] = l;
        }
        if (c0 == 0) {
#pragma unroll
          for (int nd = 0; nd < 8; ++nd)
            O[((size_t)b * SEQ + q0 + qr) * DIM + h * HD + nd * 16 + ln] =
                (bf16)o[mt][nd][r];
        } else {
#pragma unroll
          for (int nd = 0; nd < 8; ++nd)
            Op[qr * 128 + nd * 16 + ln] = (bf16)o[mt][nd][r];
        }
      }
  }
}

// ----------------------------------------------------- merge split-K partials
// grid (32, 11): bh x (t-5). Chunk 0 lives unnormalized in O; chunks 1..nc-1
// in Opart. Combine with max-rebased weights, normalize, write O.
__global__ __launch_bounds__(256) void flash_merge(const bf16* __restrict__ Opart,
                                                   const float* __restrict__ Mpart,
                                                   const float* __restrict__ Lpart,
                                                   bf16* __restrict__ O) {
  const int bh = blockIdx.x;
  const int t = 5 + blockIdx.y;
  const int nc = (t < 10) ? 2 : (t < 15) ? 3 : 4;
  const int b = bh >> 4, h = bh & 15;
  const int row = threadIdx.x >> 1, half = threadIdx.x & 1;
  const int mlb = bh * 29 + ml_off(t);
  float m[4], l[4], wt[4];
  float M = -1e30f;
  for (int c = 0; c < nc; ++c) {
    m[c] = Mpart[(mlb + c) * 128 + row];
    l[c] = Lpart[(mlb + c) * 128 + row];
    M = fmaxf(M, m[c]);
  }
  float wsum = 0.f;
  for (int c = 0; c < nc; ++c) { wt[c] = exp2f(m[c] - M); wsum += wt[c] * l[c]; }
  const float inv = 1.f / wsum;
  bf16* dst = O + ((size_t)b * SEQ + t * 128 + row) * DIM + h * HD + half * 64;
  const bf16* pb = Opart + (size_t)(bh * 18 + op_off(t)) * (128 * 128) + row * 128 + half * 64;
#pragma unroll
  for (int j = 0; j < 8; ++j) {
    bf16x8 a0 = *(const bf16x8*)(dst + j * 8);
    float acc[8];
#pragma unroll
    for (int k = 0; k < 8; ++k) acc[k] = wt[0] * (float)a0[k];
    for (int c = 1; c < nc; ++c) {
      bf16x8 a = *(const bf16x8*)(pb + (size_t)(c - 1) * (128 * 128) + j * 8);
#pragma unroll
      for (int k = 0; k < 8; ++k) acc[k] += wt[c] * (float)a[k];
    }
    bf16x8 o8;
#pragma unroll
    for (int k = 0; k < 8; ++k) o8[k] = (bf16)(acc[k] * inv);
    *(bf16x8*)(dst + j * 8) = o8;
  }
}

// ------------------------------------------------------------------- launch
extern "C" void kernel_launch(void* const* d_in, const int* in_sizes, int n_in,
                              void* d_out, int out_size, void* d_ws, size_t ws_size,
                              hipStream_t stream) {
  (void)in_sizes; (void)n_in; (void)out_size; (void)ws_size;
  const float* x  = (const float*)d_in[0];
  const float* Wq = (const float*)d_in[1];
  const float* Wk = (const float*)d_in[2];
  const float* Wv = (const float*)d_in[3];
  const float* Wo = (const float*)d_in[4];

  char* ws = (char*)d_ws;
  const size_t MB = 1u << 20;
  const size_t WB = (size_t)DIM * DIM * 2;  // 8 MB
  bf16* WTqkv = (bf16*)(ws);                // 24 MB; dead after gemm_qkv
  bf16* WoT   = (bf16*)(ws + 3 * WB);       // 8 MB
  bf16* xb    = (bf16*)(ws + 32 * MB);      // 16 MB; Ab aliases after QKV
  bf16* Qb    = (bf16*)(ws + 48 * MB);
  bf16* Kb    = (bf16*)(ws + 64 * MB);
  bf16* VT    = (bf16*)(ws + 80 * MB);
  bf16* Ab    = xb;
  // split-K partials alias the (dead) WTqkv region:
  // Opart 18.9 MB (32 bh x 18 slots x 32 KB) + M/L ~0.5 MB each
  bf16*  Opart = (bf16*)(ws);
  float* Mpart = (float*)(ws + 19 * MB);
  float* Lpart = (float*)(ws + 19 * MB + 512 * 1024);

  int n4 = BATCH * SEQ * DIM / 4;
  cvt_f32_to_bf16<<<n4 / 256, 256, 0, stream>>>((const float4*)x, (bf16x4*)xb, n4);
  dim3 tb(32, 8), tg(DIM / 32, DIM / 32, 4);
  transpose_w4<<<tg, tb, 0, stream>>>(Wq, Wk, Wv, Wo, WTqkv, WoT);

  // 256x256 8-phase QKV: 1-D grid of 24x16 tiles, XCD-bijective swizzle in-kernel
  gemm_qkv<<<24 * 16, 512, 0, stream>>>(xb, WTqkv, Qb, Kb, VT);

  // 1-D XCD-swizzled flash grid: 34 chunks x 32 bh
  flash_attn<<<34 * BATCH * NH, 256, 0, stream>>>(Qb, Kb, VT, Ab, Opart, Mpart, Lpart);
  dim3 mg(BATCH * NH, 11);
  flash_merge<<<mg, 256, 0, stream>>>(Opart, Mpart, Lpart, Ab);

  dim3 gg(DIM / 128, BATCH * SEQ / 128);
  gemm_bt<2><<<gg, 256, 0, stream>>>(Ab, WoT, d_out);
}

// Round 2
// 442.725 us; speedup vs baseline: 1.0352x; 1.0352x over previous
//
#include <hip/hip_runtime.h>
#include <hip/hip_bf16.h>
#include <math.h>

typedef __bf16 bf16;
typedef __attribute__((ext_vector_type(2))) __bf16 bf16x2;
typedef __attribute__((ext_vector_type(4))) __bf16 bf16x4;
typedef __attribute__((ext_vector_type(8))) __bf16 bf16x8;
typedef __attribute__((ext_vector_type(4))) float f32x4;

#define LDS_ASYNC16(gptr, lptr)                                                        \
  __builtin_amdgcn_global_load_lds(                                                    \
      (const __attribute__((address_space(1))) void*)(gptr),                           \
      (__attribute__((address_space(3))) void*)(lptr), 16, 0, 0)

constexpr int BATCH = 2, SEQ = 2048, DIM = 2048, NH = 16, HD = 128;
// 1/sqrt(128) * log2(e): folded into Q at projection; flash works in exp2 domain
constexpr float QSC = 0.12751744f;
constexpr float FREQC = 0.20762050593046f;  // log2(10000)/64

// ---- DPP 16-lane reductions (row_ror rotates within 16-lane rows on gfx9) ----
template <int CTRL>
__device__ __forceinline__ float dpp_mov_f(float x) {
  return __int_as_float(__builtin_amdgcn_update_dpp(
      __float_as_int(x), __float_as_int(x), CTRL, 0xf, 0xf, false));
}
__device__ __forceinline__ float rowmax16(float x) {
  x = fmaxf(x, dpp_mov_f<0x121>(x));  // ror:1
  x = fmaxf(x, dpp_mov_f<0x122>(x));  // ror:2
  x = fmaxf(x, dpp_mov_f<0x124>(x));  // ror:4
  x = fmaxf(x, dpp_mov_f<0x128>(x));  // ror:8
  return x;
}
__device__ __forceinline__ float rowsum16(float x) {
  x += dpp_mov_f<0x121>(x);
  x += dpp_mov_f<0x122>(x);
  x += dpp_mov_f<0x124>(x);
  x += dpp_mov_f<0x128>(x);
  return x;
}

// ---------------------------------------------------------------- fp32 -> bf16
__global__ void cvt_f32_to_bf16(const float4* __restrict__ in,
                                bf16x4* __restrict__ out, int n4) {
  int i = blockIdx.x * blockDim.x + threadIdx.x;
  if (i >= n4) return;
  float4 v = in[i];
  bf16x4 o;
  o[0] = (bf16)v.x; o[1] = (bf16)v.y; o[2] = (bf16)v.z; o[3] = (bf16)v.w;
  out[i] = o;
}

// ------------------------- all 4 weights: W (K,N) fp32 -> W^T (N,K) bf16, z=which
__global__ void transpose_w4(const float* __restrict__ W0, const float* __restrict__ W1,
                             const float* __restrict__ W2, const float* __restrict__ W3,
                             bf16* __restrict__ T0, bf16* __restrict__ T3) {
  __shared__ float tile[32][33];
  const int z = blockIdx.z;
  const float* W = (z == 0) ? W0 : (z == 1) ? W1 : (z == 2) ? W2 : W3;
  bf16* WT = (z == 3) ? T3 : (T0 + (size_t)z * DIM * DIM);
  int tx = threadIdx.x, ty = threadIdx.y;
  int bx = blockIdx.x * 32, by = blockIdx.y * 32;
#pragma unroll
  for (int j = 0; j < 32; j += 8)
    tile[ty + j][tx] = W[(size_t)(by + ty + j) * DIM + bx + tx];
  __syncthreads();
#pragma unroll
  for (int j = 0; j < 32; j += 8)
    WT[(size_t)(bx + ty + j) * DIM + by + tx] = (bf16)tile[tx][ty + j];
}

// ===================== 128x256 2-phase-counted fused QKV GEMM + RoPE ==========
// BM=128, BN=256, BK=64, 512 thr = 8 waves (2M x 4N), wave tile 64x64.
// Grid 32x24 = 768 blocks = EXACTLY 3 rounds of 256 CUs (the 256x256 version's
// 384 blocks at 1 block/CU lost 25% to makespan quantization -- r1 post-mortem).
// LDS 96 KB: A regions (buf,kh) 128x32 = 8 KB x4; B regions 256x32 = 16 KB x4.
// Chunk swizzle: phys 16B-chunk p at (row, logical kc): p = kc ^ ((row>>1)&3).
// Per K-tile t (buf b=t&1), 2 phases:
//   P1 reads A(b,0)+B(b,0) frags; stages (t+1,kh1) [3 instrs; regions freed (t-1).P2]
//   P2 reads A(b,1)+B(b,1) frags; stages (t+2,kh0) [3 instrs; regions freed P1]
//   tile-end s_waitcnt vmcnt(3): newest 3 = P2's (t+2,0) stay in flight; all of
//   tile t+1 ((t+1,0) staged (t-1).P2, (t+1,1) staged t.P1) has landed.
__device__ __forceinline__ void stage_A(const bf16* __restrict__ src, int g0, int ks,
                                        bf16* lds, int w, int lane) {
  const int u = w * 64 + lane;              // 16B-slot 0..511 (one instr: 8 KB)
  const int row = u >> 2;                   // 4 chunks/row
  const int kc = (u & 3) ^ ((u >> 3) & 3);  // inverse swizzle on SOURCE
  LDS_ASYNC16(src + (size_t)(g0 + row) * DIM + ks + kc * 8,
              lds + (size_t)(w * 64) * 8);  // linear LDS dest (+lane*16B in HW)
}
__device__ __forceinline__ void stage_B(const bf16* __restrict__ src, int g0, int ks,
                                        bf16* lds, int w, int lane) {
#pragma unroll
  for (int j = 0; j < 2; ++j) {             // two instrs: 16 KB
    const int u = (j * 8 + w) * 64 + lane;
    const int row = u >> 2;
    const int kc = (u & 3) ^ ((u >> 3) & 3);
    LDS_ASYNC16(src + (size_t)(g0 + row) * DIM + ks + kc * 8,
                lds + (size_t)((j * 8 + w) * 64) * 8);
  }
}

__global__ __launch_bounds__(512) void gemm_qkv(const bf16* __restrict__ A,
                                                const bf16* __restrict__ BT,
                                                bf16* __restrict__ Qb,
                                                bf16* __restrict__ Kb,
                                                bf16* __restrict__ VTo) {
  constexpr int ARSZ = 128 * 32;  // 8 KB region
  constexpr int BRSZ = 256 * 32;  // 16 KB region
  constexpr int NT = DIM / 64;    // 32 K-tiles
  __shared__ __attribute__((aligned(16))) bf16 As[4 * ARSZ];  // 32 KB
  __shared__ __attribute__((aligned(16))) bf16 Bs[4 * BRSZ];  // 64 KB
  const int tid = threadIdx.x;
  const int w = tid >> 6, lane = tid & 63;
  const int quad = lane >> 4, ln = lane & 15;
  const int wm = w >> 2, wn = w & 3;  // 2M x 4N wave grid
  // XCD-bijective swizzle: xcd owns an 8(by) x 12(bx) panel block -> per-XCD L2
  // holds 8 A-panels (4 MB) across all 3 dispatch rounds + streams 12 B-panels.
  const int lb = blockIdx.x;
  const int xcd = lb & 7, i = lb >> 3;       // i in 0..95
  const int by = (xcd >> 1) * 8 + (i & 7);   // 0..31
  const int bx = (xcd & 1) * 12 + (i >> 3);  // 0..23
  const int m0 = by * 128, n0 = bx * 256;
  const int pc = (quad ^ ((ln >> 1) & 3)) * 8;  // swizzled read chunk (lane-const)
  const int aoff = wm * 64 + ln;
  const int boff = wn * 64 + ln;

  f32x4 acc[4][4] = {};

  // prologue: (0,0) (0,1) (1,0); vmcnt(3) leaves (1,0)'s 3 in flight
  stage_A(A,  m0, 0,  As + 0 * ARSZ, w, lane);
  stage_B(BT, n0, 0,  Bs + 0 * BRSZ, w, lane);
  stage_A(A,  m0, 32, As + 1 * ARSZ, w, lane);
  stage_B(BT, n0, 32, Bs + 1 * BRSZ, w, lane);
  stage_A(A,  m0, 64, As + 2 * ARSZ, w, lane);
  stage_B(BT, n0, 64, Bs + 2 * BRSZ, w, lane);
  asm volatile("s_waitcnt vmcnt(3)" ::: "memory");
  __builtin_amdgcn_s_barrier();

#pragma unroll 2
  for (int t = 0; t < NT; ++t) {
    const int b2 = (t & 1) * 2;
    const bf16* Ab0 = As + b2 * ARSZ;
    const bf16* Ab1 = Ab0 + ARSZ;
    const bf16* Bb0 = Bs + b2 * BRSZ;
    const bf16* Bb1 = Bb0 + BRSZ;
    bf16x8 af[4], bfr[4];

    // ---- P1: kh0
#pragma unroll
    for (int f = 0; f < 4; ++f)
      af[f] = *(const bf16x8*)(Ab0 + (aoff + f * 16) * 32 + pc);
#pragma unroll
    for (int f = 0; f < 4; ++f)
      bfr[f] = *(const bf16x8*)(Bb0 + (boff + f * 16) * 32 + pc);
    if (t + 1 < NT) {
      const int r1 = ((t + 1) & 1) * 2 + 1;
      stage_A(A,  m0, (t + 1) * 64 + 32, As + r1 * ARSZ, w, lane);
      stage_B(BT, n0, (t + 1) * 64 + 32, Bs + r1 * BRSZ, w, lane);
    }
    __builtin_amdgcn_s_barrier();
    asm volatile("s_waitcnt lgkmcnt(0)" ::: "memory");
    __builtin_amdgcn_s_setprio(1);
#pragma unroll
    for (int mf = 0; mf < 4; ++mf)
#pragma unroll
      for (int nf = 0; nf < 4; ++nf)
        acc[mf][nf] = __builtin_amdgcn_mfma_f32_16x16x32_bf16(
            af[mf], bfr[nf], acc[mf][nf], 0, 0, 0);
    __builtin_amdgcn_s_setprio(0);
    __builtin_amdgcn_s_barrier();

    // ---- P2: kh1
#pragma unroll
    for (int f = 0; f < 4; ++f)
      af[f] = *(const bf16x8*)(Ab1 + (aoff + f * 16) * 32 + pc);
#pragma unroll
    for (int f = 0; f < 4; ++f)
      bfr[f] = *(const bf16x8*)(Bb1 + (boff + f * 16) * 32 + pc);
    if (t + 2 < NT) {
      stage_A(A,  m0, (t + 2) * 64, As + b2 * ARSZ, w, lane);
      stage_B(BT, n0, (t + 2) * 64, Bs + b2 * BRSZ, w, lane);
    }
    __builtin_amdgcn_s_barrier();
    asm volatile("s_waitcnt lgkmcnt(0)" ::: "memory");
    __builtin_amdgcn_s_setprio(1);
#pragma unroll
    for (int mf = 0; mf < 4; ++mf)
#pragma unroll
      for (int nf = 0; nf < 4; ++nf)
        acc[mf][nf] = __builtin_amdgcn_mfma_f32_16x16x32_bf16(
            af[mf], bfr[nf], acc[mf][nf], 0, 0, 0);
    __builtin_amdgcn_s_setprio(0);
    if (t + 2 < NT) asm volatile("s_waitcnt vmcnt(3)" ::: "memory");
    else            asm volatile("s_waitcnt vmcnt(0)" ::: "memory");
    __builtin_amdgcn_s_barrier();
  }

  // ---------------- epilogue: Q (RoPE*QSC) / K (RoPE) / V^T ----------------
  const int sel = n0 >> 11;  // bx 0-7: Q, 8-15: K, 16-23: V (block-uniform)
  if (sel == 2) {
#pragma unroll
    for (int mf = 0; mf < 4; ++mf)
#pragma unroll
      for (int nf = 0; nf < 4; ++nf) {
        int gr = m0 + wm * 64 + mf * 16 + quad * 4;
        int fc = (n0 + wn * 64 + nf * 16 + ln) & 2047;
        int bb = gr >> 11, s0 = gr & (SEQ - 1);
        int h = fc >> 7, d = fc & (HD - 1);
        bf16x4 pk;
#pragma unroll
        for (int r = 0; r < 4; ++r) pk[r] = (bf16)acc[mf][nf][r];
        *(bf16x4*)(VTo + ((size_t)((bb * NH + h) * HD + d)) * SEQ + s0) = pk;
      }
  } else {
    bf16* Dst = sel ? Kb : Qb;
    const float osc = sel ? 1.0f : QSC;
#pragma unroll
    for (int nf = 0; nf < 4; ++nf) {
      int gc = n0 + wn * 64 + nf * 16 + ln;
      int fc = gc & 2047, d = fc & (HD - 1);
      float freq = exp2f(-(float)(d >> 1) * FREQC);
      bool ev = !(d & 1);
#pragma unroll
      for (int mf = 0; mf < 4; ++mf) {
#pragma unroll
        for (int r = 0; r < 4; ++r) {
          int gr = m0 + wm * 64 + mf * 16 + quad * 4 + r;
          int s = gr & (SEQ - 1);
          float ang = (float)s * freq;
          float sn, cs;
          __sincosf(ang, &sn, &cs);
          float own = acc[mf][nf][r];
          float oth = __shfl_xor(own, 1);  // partner feature (d^1), lane ln^1
          float res = ev ? (own * cs - oth * sn) : (oth * sn + own * cs);
          Dst[(size_t)gr * DIM + fc] = (bf16)(res * osc);
        }
      }
    }
  }
}

// --------------------------------------------------------------------- GEMM
// C[M,N] = A * BT^T; MODE 2: C fp32 row-major (used for the Wo projection).
template <int MODE>
__global__ __launch_bounds__(256) void gemm_bt(const bf16* __restrict__ A,
                                               const bf16* __restrict__ BT,
                                               void* __restrict__ C) {
  __shared__ __attribute__((aligned(16))) bf16 As[128 * 64];
  __shared__ __attribute__((aligned(16))) bf16 Bs[128 * 64];
  const int tid = threadIdx.x;
  const int w = tid >> 6, lane = tid & 63;
  const int quad = lane >> 4, ln = lane & 15;
  const int m0 = blockIdx.y * 128, n0 = blockIdx.x * 128;
  const int wm = (w >> 1) * 64, wn = (w & 1) * 64;
  const int l7 = ln & 7;
  f32x4 acc[4][4] = {};

  for (int k0 = 0; k0 < DIM; k0 += 64) {
#pragma unroll
    for (int i = 0; i < 4; ++i) {
      const int c = i * 256 + tid;
      const int row = c >> 3, p = c & 7;
      LDS_ASYNC16(A  + (size_t)(m0 + row) * DIM + k0 + ((p ^ (row & 7)) * 8),
                  As + (size_t)(i * 256 + w * 64) * 8);
      LDS_ASYNC16(BT + (size_t)(n0 + row) * DIM + k0 + ((p ^ (row & 7)) * 8),
                  Bs + (size_t)(i * 256 + w * 64) * 8);
    }
    __syncthreads();
#pragma unroll
    for (int kh = 0; kh < 2; ++kh) {
      bf16x8 af[4], bfr[4];
#pragma unroll
      for (int t = 0; t < 4; ++t)
        af[t] = *(const bf16x8*)(As + (wm + t * 16 + ln) * 64 +
                                 (((kh * 4 + quad) ^ l7) * 8));
#pragma unroll
      for (int t = 0; t < 4; ++t)
        bfr[t] = *(const bf16x8*)(Bs + (wn + t * 16 + ln) * 64 +
                                  (((kh * 4 + quad) ^ l7) * 8));
#pragma unroll
      for (int mt = 0; mt < 4; ++mt)
#pragma unroll
        for (int nt = 0; nt < 4; ++nt)
          acc[mt][nt] = __builtin_amdgcn_mfma_f32_16x16x32_bf16(
              af[mt], bfr[nt], acc[mt][nt], 0, 0, 0);
    }
    __syncthreads();
  }

  if (MODE == 0) {
    bf16* Co = (bf16*)C;
#pragma unroll
    for (int mt = 0; mt < 4; ++mt)
#pragma unroll
      for (int nt = 0; nt < 4; ++nt) {
        int gr = m0 + wm + mt * 16 + quad * 4;
        int gc = n0 + wn + nt * 16 + ln;
#pragma unroll
        for (int r = 0; r < 4; ++r)
          Co[(size_t)(gr + r) * DIM + gc] = (bf16)acc[mt][nt][r];
      }
  } else {
    float* Co = (float*)C;
#pragma unroll
    for (int mt = 0; mt < 4; ++mt)
#pragma unroll
      for (int nt = 0; nt < 4; ++nt) {
        int gr = m0 + wm + mt * 16 + quad * 4;
        int gc = n0 + wn + nt * 16 + ln;
#pragma unroll
        for (int r = 0; r < 4; ++r)
          Co[(size_t)(gr + r) * DIM + gc] = acc[mt][nt][r];
      }
  }
}

// -------------------------- flash split-K chunk bookkeeping (chunk = 10 k-tiles)
// Per (b,h): t=0..4 direct (1 chunk); t=5..9: 2 chunks; t=10..14: 3; t=15: 4.
// 34 blocks/bh. Chunk 0 of a chunked tile writes unnormalized bf16 into O's
// final location; chunks >=1 go to Opart. All chunks write M/L.
__device__ __forceinline__ int ml_off(int t) {  // per-bh M/L slot base, stride 29
  return (t < 10) ? 2 * (t - 5) : (t < 15) ? 10 + 3 * (t - 10) : 25;
}
__device__ __forceinline__ int op_off(int t) {  // per-bh Opart slot base, stride 18
  return (t < 10) ? (t - 5) : (t < 15) ? 5 + 2 * (t - 10) : 15;
}

constexpr int PSTR = 72;
// 1-D grid, XCD-swizzled: lb = ((bh>>3)*34 + e)*8 + (bh&7), so lb%8 (the XCD
// on the 8-XCD round-robin) is constant per bh -> one bh's 1 MB of K/V stays
// in one XCD's L2 (4 bh x 1 MB per XCD) instead of being fetched by all 8.
__global__ __launch_bounds__(256) void flash_attn(
    const bf16* __restrict__ Q, const bf16* __restrict__ K,
    const bf16* __restrict__ VT, bf16* __restrict__ O,
    bf16* __restrict__ Opart, float* __restrict__ Mpart,
    float* __restrict__ Lpart) {
  __shared__ __attribute__((aligned(16))) bf16 Ks[64 * 128];
  __shared__ __attribute__((aligned(16))) bf16 VTs[128 * 64];
  __shared__ __attribute__((aligned(16))) bf16 Ps[4][32 * PSTR];
  const int tid = threadIdx.x;
  const int w = tid >> 6, lane = tid & 63, quad = lane >> 4, ln = lane & 15;
  const int lb = blockIdx.x;
  const int low3 = lb & 7, rest = lb >> 3;
  const int e = rest % 34;
  const int bh = (rest / 34) * 8 + low3;
  int t, c0, nc;
  if (e < 5)       { t = e;                  c0 = 0;               nc = 1; }
  else if (e < 15) { t = 5 + ((e - 5) >> 1); c0 = (e - 5) & 1;     nc = 2; }
  else if (e < 30) { int q = (e - 15) / 3;   t = 10 + q; c0 = (e - 15) - 3 * q; nc = 3; }
  else             { t = 15;                 c0 = e - 30;          nc = 4; }
  const int q0 = t * 128;
  const int ktN = 2 * (t + 1);
  const int kt0 = c0 * 10;
  const int kt1 = min(kt0 + 10, ktN);
  const bool chunked = (nc > 1);
  const int b = bh >> 4, h = bh & 15;

  bf16x8 qf[2][4];
#pragma unroll
  for (int mt = 0; mt < 2; ++mt)
#pragma unroll
    for (int kc = 0; kc < 4; ++kc)
      qf[mt][kc] = *(const bf16x8*)(Q + ((size_t)b * SEQ + q0 + w * 32 + mt * 16 + ln) * DIM +
                                    h * HD + kc * 32 + quad * 8);
  f32x4 o[2][8] = {};
  float mst[2][4], lst[2][4];
#pragma unroll
  for (int mt = 0; mt < 2; ++mt)
#pragma unroll
    for (int r = 0; r < 4; ++r) { mst[mt][r] = -1e30f; lst[mt][r] = 0.f; }

  for (int kt = kt0; kt < kt1; ++kt) {
    __syncthreads();
#pragma unroll
    for (int i = 0; i < 4; ++i) {
      const int c = i * 256 + tid;
      LDS_ASYNC16(K + ((size_t)b * SEQ + kt * 64 + (c >> 4)) * DIM + h * HD +
                      (((c & 15) ^ ((c >> 4) & 15)) * 8),
                  Ks + (size_t)(i * 256 + w * 64) * 8);
      LDS_ASYNC16(VT + ((size_t)((b * NH + h) * HD) + (c >> 3)) * SEQ + kt * 64 +
                      (((c & 7) ^ ((c >> 3) & 7)) * 8),
                  VTs + (size_t)(i * 256 + w * 64) * 8);
    }
    __syncthreads();

    // S = Q K^T (exp2 domain; scale pre-folded into Q)
    f32x4 s[2][4] = {};
#pragma unroll
    for (int nt = 0; nt < 4; ++nt) {
      bf16x8 kf[4];
#pragma unroll
      for (int kc = 0; kc < 4; ++kc)
        kf[kc] = *(const bf16x8*)(Ks + (nt * 16 + ln) * 128 +
                                  (((kc * 4 + quad) ^ ln) * 8));
#pragma unroll
      for (int kc = 0; kc < 4; ++kc)
#pragma unroll
        for (int mt = 0; mt < 2; ++mt)
          s[mt][nt] = __builtin_amdgcn_mfma_f32_16x16x32_bf16(
              qf[mt][kc], kf[kc], s[mt][nt], 0, 0, 0);
    }

    const bool diag = (kt * 64 + 63 > q0);
    if (diag) {
#pragma unroll
      for (int mt = 0; mt < 2; ++mt)
#pragma unroll
        for (int nt = 0; nt < 4; ++nt)
#pragma unroll
          for (int r = 0; r < 4; ++r) {
            int kg = kt * 64 + nt * 16 + ln;
            int qg = q0 + w * 32 + mt * 16 + quad * 4 + r;
            if (kg > qg) s[mt][nt][r] = -1e30f;
          }
    }

    // online softmax, exp2 domain; DPP 16-lane max (no LDS shuffles)
#pragma unroll
    for (int mt = 0; mt < 2; ++mt)
#pragma unroll
      for (int r = 0; r < 4; ++r) {
        float rm = fmaxf(fmaxf(s[mt][0][r], s[mt][1][r]),
                         fmaxf(s[mt][2][r], s[mt][3][r]));
        rm = rowmax16(rm);
        float mold = mst[mt][r];
        float mnew = fmaxf(mold, rm);
        float alpha = exp2f(mold - mnew);
        mst[mt][r] = mnew;
        float rs = 0.f;
#pragma unroll
        for (int nt = 0; nt < 4; ++nt) {
          float p = exp2f(s[mt][nt][r] - mnew);
          rs += p;
          Ps[w][(mt * 16 + quad * 4 + r) * PSTR + nt * 16 + ln] = (bf16)p;
        }
        lst[mt][r] = lst[mt][r] * alpha + rs;
#pragma unroll
        for (int nd = 0; nd < 8; ++nd) o[mt][nd][r] *= alpha;
      }
    __syncthreads();

    // O += P V
#pragma unroll
    for (int kc2 = 0; kc2 < 2; ++kc2) {
      bf16x8 pf[2];
#pragma unroll
      for (int mt = 0; mt < 2; ++mt)
        pf[mt] = *(const bf16x8*)(&Ps[w][(mt * 16 + ln) * PSTR + kc2 * 32 + quad * 8]);
#pragma unroll
      for (int nd = 0; nd < 8; ++nd) {
        bf16x8 vf = *(const bf16x8*)(VTs + (nd * 16 + ln) * 64 +
                                     (((kc2 * 4 + quad) ^ (ln & 7)) * 8));
#pragma unroll
        for (int mt = 0; mt < 2; ++mt)
          o[mt][nd] = __builtin_amdgcn_mfma_f32_16x16x32_bf16(
              pf[mt], vf, o[mt][nd], 0, 0, 0);
      }
    }
  }

  if (!chunked) {
#pragma unroll
    for (int mt = 0; mt < 2; ++mt)
#pragma unroll
      for (int r = 0; r < 4; ++r) {
        float inv = 1.f / rowsum16(lst[mt][r]);
        int qg = q0 + w * 32 + mt * 16 + quad * 4 + r;
#pragma unroll
        for (int nd = 0; nd < 8; ++nd)
          O[((size_t)b * SEQ + qg) * DIM + h * HD + nd * 16 + ln] =
              (bf16)(o[mt][nd][r] * inv);
      }
  } else {
    const int mls = bh * 29 + ml_off(t) + c0;
    bf16* Op = (c0 == 0) ? nullptr
                         : Opart + (size_t)(bh * 18 + op_off(t) + (c0 - 1)) * (128 * 128);
#pragma unroll
    for (int mt = 0; mt < 2; ++mt)
#pragma unroll
      for (int r = 0; r < 4; ++r) {
        float l = rowsum16(lst[mt][r]);
        int qr = w * 32 + mt * 16 + quad * 4 + r;
        if (ln == 0) {
          Mpart[mls * 128 + qr] = mst[mt][r];
          Lpart[mls * 128 + qr] = l;
        }
        if (c0 == 0) {
#pragma unroll
          for (int nd = 0; nd < 8; ++nd)
            O[((size_t)b * SEQ + q0 + qr) * DIM + h * HD + nd * 16 + ln] =
                (bf16)o[mt][nd][r];
        } else {
#pragma unroll
          for (int nd = 0; nd < 8; ++nd)
            Op[qr * 128 + nd * 16 + ln] = (bf16)o[mt][nd][r];
        }
      }
  }
}

// ----------------------------------------------------- merge split-K partials
// grid (32, 11): bh x (t-5). Chunk 0 lives unnormalized in O; chunks 1..nc-1
// in Opart. Combine with max-rebased weights, normalize, write O.
__global__ __launch_bounds__(256) void flash_merge(const bf16* __restrict__ Opart,
                                                   const float* __restrict__ Mpart,
                                                   const float* __restrict__ Lpart,
                                                   bf16* __restrict__ O) {
  const int bh = blockIdx.x;
  const int t = 5 + blockIdx.y;
  const int nc = (t < 10) ? 2 : (t < 15) ? 3 : 4;
  const int b = bh >> 4, h = bh & 15;
  const int row = threadIdx.x >> 1, half = threadIdx.x & 1;
  const int mlb = bh * 29 + ml_off(t);
  float m[4], l[4], wt[4];
  float M = -1e30f;
  for (int c = 0; c < nc; ++c) {
    m[c] = Mpart[(mlb + c) * 128 + row];
    l[c] = Lpart[(mlb + c) * 128 + row];
    M = fmaxf(M, m[c]);
  }
  float wsum = 0.f;
  for (int c = 0; c < nc; ++c) { wt[c] = exp2f(m[c] - M); wsum += wt[c] * l[c]; }
  const float inv = 1.f / wsum;
  bf16* dst = O + ((size_t)b * SEQ + t * 128 + row) * DIM + h * HD + half * 64;
  const bf16* pb = Opart + (size_t)(bh * 18 + op_off(t)) * (128 * 128) + row * 128 + half * 64;
#pragma unroll
  for (int j = 0; j < 8; ++j) {
    bf16x8 a0 = *(const bf16x8*)(dst + j * 8);
    float acc[8];
#pragma unroll
    for (int k = 0; k < 8; ++k) acc[k] = wt[0] * (float)a0[k];
    for (int c = 1; c < nc; ++c) {
      bf16x8 a = *(const bf16x8*)(pb + (size_t)(c - 1) * (128 * 128) + j * 8);
#pragma unroll
      for (int k = 0; k < 8; ++k) acc[k] += wt[c] * (float)a[k];
    }
    bf16x8 o8;
#pragma unroll
    for (int k = 0; k < 8; ++k) o8[k] = (bf16)(acc[k] * inv);
    *(bf16x8*)(dst + j * 8) = o8;
  }
}

// ------------------------------------------------------------------- launch
extern "C" void kernel_launch(void* const* d_in, const int* in_sizes, int n_in,
                              void* d_out, int out_size, void* d_ws, size_t ws_size,
                              hipStream_t stream) {
  (void)in_sizes; (void)n_in; (void)out_size; (void)ws_size;
  const float* x  = (const float*)d_in[0];
  const float* Wq = (const float*)d_in[1];
  const float* Wk = (const float*)d_in[2];
  const float* Wv = (const float*)d_in[3];
  const float* Wo = (const float*)d_in[4];

  char* ws = (char*)d_ws;
  const size_t MB = 1u << 20;
  const size_t WB = (size_t)DIM * DIM * 2;  // 8 MB
  bf16* WTqkv = (bf16*)(ws);                // 24 MB; dead after gemm_qkv
  bf16* WoT   = (bf16*)(ws + 3 * WB);       // 8 MB
  bf16* xb    = (bf16*)(ws + 32 * MB);      // 16 MB; Ab aliases after QKV
  bf16* Qb    = (bf16*)(ws + 48 * MB);
  bf16* Kb    = (bf16*)(ws + 64 * MB);
  bf16* VT    = (bf16*)(ws + 80 * MB);
  bf16* Ab    = xb;
  // split-K partials alias the (dead) WTqkv region:
  // Opart 18.9 MB (32 bh x 18 slots x 32 KB) + M/L ~0.5 MB each
  bf16*  Opart = (bf16*)(ws);
  float* Mpart = (float*)(ws + 19 * MB);
  float* Lpart = (float*)(ws + 19 * MB + 512 * 1024);

  int n4 = BATCH * SEQ * DIM / 4;
  cvt_f32_to_bf16<<<n4 / 256, 256, 0, stream>>>((const float4*)x, (bf16x4*)xb, n4);
  dim3 tb(32, 8), tg(DIM / 32, DIM / 32, 4);
  transpose_w4<<<tg, tb, 0, stream>>>(Wq, Wk, Wv, Wo, WTqkv, WoT);

  // 128x256 2-phase-counted QKV: 768 blocks = exactly 3 rounds of 256 CUs
  gemm_qkv<<<768, 512, 0, stream>>>(xb, WTqkv, Qb, Kb, VT);

  // 1-D XCD-swizzled flash grid: 34 chunks x 32 bh
  flash_attn<<<34 * BATCH * NH, 256, 0, stream>>>(Qb, Kb, VT, Ab, Opart, Mpart, Lpart);
  dim3 mg(BATCH * NH, 11);
  flash_merge<<<mg, 256, 0, stream>>>(Opart, Mpart, Lpart, Ab);

  dim3 gg(DIM / 128, BATCH * SEQ / 128);
  gemm_bt<2><<<gg, 256, 0, stream>>>(Ab, WoT, d_out);
}